// Round 6
// baseline (297.025 us; speedup 1.0000x reference)
//
#include <hip/hip_runtime.h>
#include <hip/hip_fp16.h>

// Problem constants (match reference)
#define NC 128
#define NS 2048
#define NX 256
#define NZ 512
#define NROWS (NX * NZ)      // 131072 output pixels
#define NCOLS (NS * NC)      // 262144 rhs rows
#define RUN 8                // contiguous nnz per lane per tile
#define TILE_NNZ (RUN * 64)  // 512 nnz per tile
#define NT 4                 // tiles per wave (pipelined)
#define WAVE_RANGE (NT * TILE_NNZ)   // 2048 nnz per wave
#define NSLOTS 64            // LDS row-accumulator slots per wave

// NOTE: harness passes ALL integer inputs as int32.
// NOTE (r3): NT on the 8B gathers REGRESSED (+200MB) — L2 thrash.
// NOTE (r5): per-lane GLOBAL atomics: HBM-side RMW. Sink must be LDS-local.
// NOTE (r6): FAILED: "VGPR-starved MLP" via launch_bounds — allocator ignored.
// NOTE (r7): NT streams: FETCH 146->113MB, time ~unchanged.
// NOTE (r9): FAILED: L1-bypass (sc0) gathers — null.
// NOTE (r10): FAILED-silently: C-source pipeline; compiler de-pipelined it
//            (VGPR 52 vs ~110 needed). All variants pin at ~130 in-flight
//            reqs/CU ≈ 0.2 lines/cy ≈ 140us. The product waves×outstanding
//            never moved.
// NOTE (r11): hot path -> inline-asm loads + static counted s_waitcnt
//            vmcnt(N) (never 0 until last tile), sched_barrier(0) after
//            every wait (rule #18: compiler hoists reg-only consumers past
//            asm waitcnt otherwise). All VMEM in fast path is asm-counted,
//            incl. rf/rl (else compiler inserts its own vmcnt(0) drain).
//            Counts monotone-safe vs rare global_flush atomics (extra
//            outstanding => stricter waits, never looser).

struct alignas(8) Half4 { __half2 lo, hi; };

typedef int   vi4 __attribute__((ext_vector_type(4)));
typedef float vf4 __attribute__((ext_vector_type(4)));

// ---- raw asm loads: manual vmcnt bookkeeping ----
__device__ __forceinline__ void ld4i(vi4& d, const int* p) {
    asm volatile("global_load_dwordx4 %0, %1, off"
                 : "=v"(d) : "v"((unsigned long long)p));
}
__device__ __forceinline__ void ld4f(vf4& d, const float* p) {
    asm volatile("global_load_dwordx4 %0, %1, off"
                 : "=v"(d) : "v"((unsigned long long)p));
}
__device__ __forceinline__ void ld1i(int& d, const int* p) {
    asm volatile("global_load_dword %0, %1, off"
                 : "=v"(d) : "v"((unsigned long long)p));
}
__device__ __forceinline__ void ld2u(unsigned long long& d, const Half4* p) {
    asm volatile("global_load_dwordx2 %0, %1, off"
                 : "=v"(d) : "v"((unsigned long long)p));
}
#define WAITV(n) do { asm volatile("s_waitcnt vmcnt(" #n ")" ::: "memory"); \
                      __builtin_amdgcn_sched_barrier(0); } while (0)

// Kernel 1: pack x (B,K,NC,NS) into fp16 rhs[j], j = s*NC + c.
__global__ void pack_rhs_kernel(const float* __restrict__ x,
                                Half4* __restrict__ rhs) {
    int j = blockIdx.x * blockDim.x + threadIdx.x;
    if (j >= NCOLS) return;
    int c = j >> 11;         // 0..127
    int s = j & (NS - 1);    // 0..2047, consecutive within wave
    int base = c * NS + s;   // coalesced across lanes
    Half4 h;
    h.lo = __float22half2_rn(make_float2(x[base],               x[base + 1 * NC * NS]));
    h.hi = __float22half2_rn(make_float2(x[base + 2 * NC * NS], x[base + 3 * NC * NS]));
    rhs[s * NC + c] = h;
}

__device__ __forceinline__ void global_flush(float* __restrict__ out, int r, float4 a) {
    int ix = r >> 9;          // r / NZ
    int iz = r & (NZ - 1);    // r % NZ
    int o = iz * NX + ix;     // out[b, iz, ix]
    atomicAdd(&out[0 * NROWS + o], a.x);
    atomicAdd(&out[1 * NROWS + o], a.y);
    atomicAdd(&out[2 * NROWS + o], a.z);
    atomicAdd(&out[3 * NROWS + o], a.w);
}

__device__ __forceinline__ void flush_slot(float (*slw)[4], int rfirst, int cur,
                                           float4 acc, float* __restrict__ out) {
    int s = cur - rfirst;
    if (s < NSLOTS) {
        atomicAdd(&slw[s][0], acc.x);
        atomicAdd(&slw[s][1], acc.y);
        atomicAdd(&slw[s][2], acc.z);
        atomicAdd(&slw[s][3], acc.w);
    } else {
        global_flush(out, cur, acc);
    }
}

// accumulate one 8-nnz tile slice held in registers
__device__ __forceinline__ void accum8(const vf4& va, const vf4& vb,
                                       const vi4& ra, const vi4& rb,
                                       const unsigned long long (&g)[8],
                                       int rfirst, int& cur, float4& acc,
                                       float* __restrict__ out, float (*slw)[4]) {
    #pragma unroll
    for (int j = 0; j < 8; ++j) {
        int   rj = (j < 4) ? ra[j] : rb[j - 4];
        float vj = (j < 4) ? va[j] : vb[j - 4];
        union { unsigned long long u; Half4 h; } u; u.u = g[j];
        float2 lo = __half22float2(u.h.lo);
        float2 hi = __half22float2(u.h.hi);
        if (rj != cur) {
            flush_slot(slw, rfirst, cur, acc, out);
            acc = make_float4(0.f, 0.f, 0.f, 0.f);
            cur = rj;
        }
        acc.x += vj * lo.x;
        acc.y += vj * lo.y;
        acc.z += vj * hi.x;
        acc.w += vj * hi.y;
    }
}

#define ISSUE_S(cx0, cx1, vx0, vx1, rx0, rx1, b) do { \
    ld4i(cx0, cols + (b));     ld4i(cx1, cols + (b) + 4); \
    ld4f(vx0, vals + (b));     ld4f(vx1, vals + (b) + 4); \
    ld4i(rx0, rows + (b));     ld4i(rx1, rows + (b) + 4); } while (0)

#define ISSUE_G(g, c0, c1) do { \
    ld2u(g[0], rhs + (c0).x);  ld2u(g[1], rhs + (c0).y); \
    ld2u(g[2], rhs + (c0).z);  ld2u(g[3], rhs + (c0).w); \
    ld2u(g[4], rhs + (c1).x);  ld2u(g[5], rhs + (c1).y); \
    ld2u(g[6], rhs + (c1).z);  ld2u(g[7], rhs + (c1).w); } while (0)

// Kernel 2 (r11): wave owns 2048 nnz = 4 tiles. All hot-path VMEM is inline
// asm with static counted vmcnt. Steady state keeps 12-18 reqs in flight per
// wave across accumulate phases. No __syncthreads; LDS slots per-wave.
__global__ void __launch_bounds__(256, 5) spmm_pipe_kernel(
        const float* __restrict__ vals,
        const int* __restrict__ cols,
        const int* __restrict__ rows,
        const Half4* __restrict__ rhs,
        float* __restrict__ out,
        int nnz) {
    __shared__ float sl[4][NSLOTS][4];   // 4KB per block, per-wave private

    int wv   = threadIdx.x >> 6;
    int lane = threadIdx.x & 63;
    int wid  = (blockIdx.x << 2) + wv;
    int wstart = wid * WAVE_RANGE;
    if (wstart >= nnz) return;

    float (*slw)[4] = sl[wv];
    *(float4*)(&slw[lane][0]) = make_float4(0.f, 0.f, 0.f, 0.f);

    if (wstart + WAVE_RANGE <= nnz) {
        // ======== fast path: fully-owned 4-tile asm pipeline ========
        const int b0 = wstart + 0 * TILE_NNZ + lane * RUN;
        const int b1 = wstart + 1 * TILE_NNZ + lane * RUN;
        const int b2 = wstart + 2 * TILE_NNZ + lane * RUN;
        const int b3 = wstart + 3 * TILE_NNZ + lane * RUN;

        int rf, rl;
        vi4 cA0, cA1, cB0, cB1;
        vf4 vA0, vA1, vB0, vB1;
        vi4 rA0, rA1, rB0, rB1;
        unsigned long long gA[8], gB[8];

        // ---- prologue ----
        ld1i(rf, rows + wstart);                       // 1
        ld1i(rl, rows + wstart + WAVE_RANGE - 1);      // 2
        ld4i(cA0, cols + b0); ld4i(cA1, cols + b0 + 4);// 4
        ld4f(vA0, vals + b0); ld4f(vA1, vals + b0 + 4);
        ld4i(rA0, rows + b0); ld4i(rA1, rows + b0 + 4);// 8 outstanding
        WAITV(4);                    // rf, rl, cA0, cA1 done
        ISSUE_G(gA, cA0, cA1);                         // 12 outstanding
        ISSUE_S(cB0, cB1, vB0, vB1, rB0, rB1, b1);     // 18 outstanding
        WAITV(14);                   // vA, rA done
        WAITV(6);                    // gA done (S(1)'s 6 remain)

        int cur = rf;
        float4 acc = make_float4(0.f, 0.f, 0.f, 0.f);

        // ---- tile 0 ----
        accum8(vA0, vA1, rA0, rA1, gA, rf, cur, acc, out, slw);
        WAITV(4);                    // cB0, cB1 done (vB/rB may remain)
        ISSUE_G(gB, cB0, cB1);                         // 12 outstanding
        ISSUE_S(cA0, cA1, vA0, vA1, rA0, rA1, b2);     // 18 outstanding
        WAITV(14);                   // vB, rB done
        WAITV(6);                    // gB done

        // ---- tile 1 ----
        accum8(vB0, vB1, rB0, rB1, gB, rf, cur, acc, out, slw);
        WAITV(4);                    // cA (t2) done
        ISSUE_G(gA, cA0, cA1);                         // 12 outstanding
        ISSUE_S(cB0, cB1, vB0, vB1, rB0, rB1, b3);     // 18 outstanding
        WAITV(14);                   // vA, rA (t2) done
        WAITV(6);                    // gA done

        // ---- tile 2 ----
        accum8(vA0, vA1, rA0, rA1, gA, rf, cur, acc, out, slw);
        WAITV(4);                    // cB (t3) done
        ISSUE_G(gB, cB0, cB1);                         // 12 outstanding
        WAITV(8);                    // vB, rB (t3) done
        WAITV(0);                    // gB done

        // ---- tile 3 ----
        accum8(vB0, vB1, rB0, rB1, gB, rf, cur, acc, out, slw);

        flush_slot(slw, rf, cur, acc, out);

        // ---- epilogue: one slot per lane (per-wave private) ----
        int span = rl - rf;
        if (lane <= span && lane < NSLOTS) {
            float ax = slw[lane][0];
            float ay = slw[lane][1];
            float az = slw[lane][2];
            float aw = slw[lane][3];
            int rr = rf + lane;
            int ix = rr >> 9;
            int iz = rr & (NZ - 1);
            int o = iz * NX + ix;
            if (lane == 0 || rr == rl) {
                atomicAdd(&out[0 * NROWS + o], ax);
                atomicAdd(&out[1 * NROWS + o], ay);
                atomicAdd(&out[2 * NROWS + o], az);
                atomicAdd(&out[3 * NROWS + o], aw);
            } else {
                out[0 * NROWS + o] = ax;
                out[1 * NROWS + o] = ay;
                out[2 * NROWS + o] = az;
                out[3 * NROWS + o] = aw;
            }
        }
    } else {
        // ======== tail path (plain HIP, bounds-checked; rare/never) ========
        int wend = nnz;
        int rf = rows[wstart];
        int rl = rows[wend - 1];
        int cur = rf;
        float4 acc = make_float4(0.f, 0.f, 0.f, 0.f);
        for (int t = 0; t < NT; ++t) {
            int tb = wstart + t * TILE_NNZ + lane * RUN;
            #pragma unroll
            for (int j = 0; j < RUN; ++j) {
                int e = tb + j;
                if (e >= nnz) break;
                float vj = vals[e];
                int   cj = cols[e];
                int   rj = rows[e];
                Half4 h = rhs[cj];
                float2 lo = __half22float2(h.lo);
                float2 hi = __half22float2(h.hi);
                if (rj != cur) {
                    flush_slot(slw, rf, cur, acc, out);
                    acc = make_float4(0.f, 0.f, 0.f, 0.f);
                    cur = rj;
                }
                acc.x += vj * lo.x;
                acc.y += vj * lo.y;
                acc.z += vj * hi.x;
                acc.w += vj * hi.y;
            }
        }
        flush_slot(slw, rf, cur, acc, out);
        int span = rl - rf;
        if (lane <= span && lane < NSLOTS) {
            int rr = rf + lane;
            int ix = rr >> 9;
            int iz = rr & (NZ - 1);
            int o = iz * NX + ix;
            // tail waves always atomic (may share rows arbitrarily)
            atomicAdd(&out[0 * NROWS + o], slw[lane][0]);
            atomicAdd(&out[1 * NROWS + o], slw[lane][1]);
            atomicAdd(&out[2 * NROWS + o], slw[lane][2]);
            atomicAdd(&out[3 * NROWS + o], slw[lane][3]);
        }
    }
}

// Fallback (workspace too small): inline bounds + direct fp32 gather from x.
__global__ void __launch_bounds__(256) spmm_direct_kernel(
        const float* __restrict__ x,
        const float* __restrict__ vals,
        const int* __restrict__ rows,
        const int* __restrict__ cols,
        int nnz,
        float* __restrict__ out) {
    int r = (blockIdx.x << 2) + (threadIdx.x >> 6);
    int lane = threadIdx.x & 63;
    int start, end;
    {
        int lo = 0, hi = nnz;
        while (lo < hi) { int mid = (lo + hi) >> 1; if (rows[mid] < r) lo = mid + 1; else hi = mid; }
        start = lo;
        hi = nnz;
        int key = r + 1;
        while (lo < hi) { int mid = (lo + hi) >> 1; if (rows[mid] < key) lo = mid + 1; else hi = mid; }
        end = lo;
    }
    float4 acc = {0.f, 0.f, 0.f, 0.f};
    for (int i = start + lane; i < end; i += 64) {
        float v = vals[i];
        int col = cols[i];
        int cc = col & (NC - 1);
        int ss = col >> 7;
        int b = cc * NS + ss;
        acc.x += v * x[b];
        acc.y += v * x[b + 1 * NC * NS];
        acc.z += v * x[b + 2 * NC * NS];
        acc.w += v * x[b + 3 * NC * NS];
    }
    #pragma unroll
    for (int off = 32; off >= 1; off >>= 1) {
        acc.x += __shfl_xor(acc.x, off, 64);
        acc.y += __shfl_xor(acc.y, off, 64);
        acc.z += __shfl_xor(acc.z, off, 64);
        acc.w += __shfl_xor(acc.w, off, 64);
    }
    if (lane < 4) {
        float o = (lane == 0) ? acc.x : (lane == 1) ? acc.y : (lane == 2) ? acc.z : acc.w;
        int ix = r >> 9;
        int iz = r & (NZ - 1);
        out[lane * NROWS + iz * NX + ix] = o;
    }
}

extern "C" void kernel_launch(void* const* d_in, const int* in_sizes, int n_in,
                              void* d_out, int out_size, void* d_ws, size_t ws_size,
                              hipStream_t stream) {
    const float* x        = (const float*)d_in[0];
    const float* csr_vals = (const float*)d_in[1];
    const int*   csr_rows = (const int*)d_in[2];   // int32 per harness contract
    const int*   csr_cols = (const int*)d_in[3];
    float* out = (float*)d_out;
    int nnz = in_sizes[1];

    size_t need = (size_t)NCOLS * sizeof(Half4);   // 2MB
    if (ws_size >= need) {
        Half4* rhs = (Half4*)d_ws;
        hipMemsetAsync(out, 0, (size_t)out_size * sizeof(float), stream);
        pack_rhs_kernel<<<(NCOLS + 255) / 256, 256, 0, stream>>>(x, rhs);
        int per_block = 4 * WAVE_RANGE;            // 4 waves x 2048 nnz
        int nblocks = (nnz + per_block - 1) / per_block;   // 2048 blocks, 8192 waves
        spmm_pipe_kernel<<<nblocks, 256, 0, stream>>>(csr_vals, csr_cols, csr_rows,
                                                      rhs, out, nnz);
    } else {
        spmm_direct_kernel<<<NROWS / 4, 256, 0, stream>>>(x, csr_vals, csr_rows, csr_cols, nnz, out);
    }
}

// Round 7
// 285.591 us; speedup vs baseline: 1.0400x; 1.0400x over previous
//
#include <hip/hip_runtime.h>
#include <hip/hip_fp16.h>

// Problem constants (match reference)
#define NC 128
#define NS 2048
#define NX 256
#define NZ 512
#define NROWS (NX * NZ)      // 131072 output pixels
#define NCOLS (NS * NC)      // 262144 rhs rows
#define RUN 8                // contiguous nnz per lane
#define WAVE_NNZ (RUN * 64)  // 512 nnz per wave
#define NSLOTS 64            // LDS row-accumulator slots per wave

// NOTE: harness passes ALL integer inputs as int32.
// NOTE (r3): nontemporal on the 8B gathers REGRESSED (+200MB) — L2 thrash.
// NOTE (r5): per-lane GLOBAL atomics: HBM-side RMW. Sink must be LDS-local.
// NOTE (r6): FAILED: "VGPR-starved MLP" — launch_bounds/sched_barrier: null.
// NOTE (r7): NT streams: FETCH 146->113MB (table stays L2-resident), -11us.
// NOTE (r8): __builtin_nontemporal_load needs ext_vector_type, not int4.
// NOTE (r9): L1-bypass (sc0) gathers: null. Cost is downstream of L1.
// NOTE (r10): C-source 4-tile pipeline: compiler de-pipelined (VGPR 52), null.
// NOTE (r11): asm loads + counted vmcnt pipeline: REGRESSED 140->170us.
//            Static WAITV schedule worse than compiler interleave.
// NOTE (r12): FINAL MODEL (7-way falsified): per-XCD L2 random-request rate
//            ~7.4 req/cy (0.23/cy/CU) is the wall. 77.5K req/CU / 0.23 =
//            337K cy = 140us = measured. Invariant to wave count (36-78%
//            occupancy), queue depth, L1 policy, pipelining. Sequential
//            requests run ~7x faster => randomness, not count. Binning into
//            LDS sub-tables prices at ~110-120us (335MB extra traffic) —
//            not worth the risk; headline dur_us is ~insensitive to spmm
//            (fixed ~285us harness floor). This file = round-4 best state.

struct alignas(8) Half4 { __half2 lo, hi; };

typedef int   vint4   __attribute__((ext_vector_type(4)));
typedef float vfloat4 __attribute__((ext_vector_type(4)));

__device__ __forceinline__ int4 nt_load_i4(const int* p) {
    vint4 t = __builtin_nontemporal_load((const vint4*)p);
    return make_int4(t.x, t.y, t.z, t.w);
}
__device__ __forceinline__ float4 nt_load_f4(const float* p) {
    vfloat4 t = __builtin_nontemporal_load((const vfloat4*)p);
    return make_float4(t.x, t.y, t.z, t.w);
}

// Gather with L1 bypass (agent-scope relaxed load -> sc0). Measured neutral
// vs plain load (r9) — kept: harmless, and keeps L1 free for the streams.
__device__ __forceinline__ Half4 gather_l1bypass(const Half4* p) {
    unsigned long long raw =
        __hip_atomic_load((const unsigned long long*)p,
                          __ATOMIC_RELAXED, __HIP_MEMORY_SCOPE_AGENT);
    union { unsigned long long u; Half4 h; } cv;
    cv.u = raw;
    return cv.h;
}

// Kernel 1: pack x (B,K,NC,NS) into fp16 rhs[j], j = s*NC + c.
// Thread mapping: consecutive lanes = consecutive s -> coalesced reads.
__global__ void pack_rhs_kernel(const float* __restrict__ x,
                                Half4* __restrict__ rhs) {
    int j = blockIdx.x * blockDim.x + threadIdx.x;
    if (j >= NCOLS) return;
    int c = j >> 11;         // 0..127
    int s = j & (NS - 1);    // 0..2047, consecutive within wave
    int base = c * NS + s;   // coalesced across lanes
    Half4 h;
    h.lo = __float22half2_rn(make_float2(x[base],               x[base + 1 * NC * NS]));
    h.hi = __float22half2_rn(make_float2(x[base + 2 * NC * NS], x[base + 3 * NC * NS]));
    rhs[s * NC + c] = h;
}

__device__ __forceinline__ void global_flush(float* __restrict__ out, int r, float4 a) {
    int ix = r >> 9;          // r / NZ
    int iz = r & (NZ - 1);    // r % NZ
    int o = iz * NX + ix;     // out[b, iz, ix]
    atomicAdd(&out[0 * NROWS + o], a.x);
    atomicAdd(&out[1 * NROWS + o], a.y);
    atomicAdd(&out[2 * NROWS + o], a.z);
    atomicAdd(&out[3 * NROWS + o], a.w);
}

// Kernel 2: wave owns 512 contiguous nnz (lane: 8). NT 16B stream loads
// (evict-first in L2), 8 independent 8B gathers (sc0), lane-local segmented
// accumulate flushed to per-wave LDS slots. Epilogue: interior rows ->
// direct store; 2 boundary rows -> global atomicAdd over memset-0 output.
__global__ void __launch_bounds__(256, 8) spmm_seg_kernel(
        const float* __restrict__ vals,
        const int* __restrict__ cols,
        const int* __restrict__ rows,
        const Half4* __restrict__ rhs,
        float* __restrict__ out,
        int nnz) {
    __shared__ float sl[4][NSLOTS][4];   // 4KB per block

    int wv   = threadIdx.x >> 6;
    int lane = threadIdx.x & 63;
    int wid  = (blockIdx.x << 2) + wv;
    int base = wid * WAVE_NNZ + lane * RUN;

    // zero this block's LDS (256 threads x 1 float4 = 4KB)
    ((float4*)sl)[threadIdx.x] = make_float4(0.f, 0.f, 0.f, 0.f);
    __syncthreads();

    // ---- stream loads: 8 nnz per lane, NT (evict-first in L2) ----
    float4 v[2];
    int4   c4[2], r4[2];
    if (base + RUN <= nnz) {
        #pragma unroll
        for (int q = 0; q < 2; ++q) c4[q] = nt_load_i4(cols + base + 4 * q);
        #pragma unroll
        for (int q = 0; q < 2; ++q) v[q]  = nt_load_f4(vals + base + 4 * q);
        #pragma unroll
        for (int q = 0; q < 2; ++q) r4[q] = nt_load_i4(rows + base + 4 * q);
    } else {
        #pragma unroll
        for (int q = 0; q < 2; ++q) {
            #pragma unroll
            for (int k = 0; k < 4; ++k) {
                int e = base + 4 * q + k;
                int ec = e < nnz ? e : (nnz - 1);
                (&v[q].x)[k]  = e < nnz ? vals[ec] : 0.f;   // v=0: contributes nothing
                (&c4[q].x)[k] = cols[ec];
                (&r4[q].x)[k] = rows[ec];
            }
        }
    }

    // ---- 8 independent 8B gathers, L1-bypass (sc0) ----
    Half4 g[RUN];
    #pragma unroll
    for (int q = 0; q < 2; ++q) {
        g[4 * q + 0] = gather_l1bypass(rhs + c4[q].x);
        g[4 * q + 1] = gather_l1bypass(rhs + c4[q].y);
        g[4 * q + 2] = gather_l1bypass(rhs + c4[q].z);
        g[4 * q + 3] = gather_l1bypass(rhs + c4[q].w);
    }
    // Pin: all loads issued before any consumption below.
    __builtin_amdgcn_sched_barrier(0);

    int rfirst = __shfl(r4[0].x, 0);     // wave's first row
    int rlast  = __shfl(r4[1].w, 63);    // wave's last row

    // ---- lane-local segmented accumulate, flush to LDS slots ----
    int cur = r4[0].x;
    float4 acc = make_float4(0.f, 0.f, 0.f, 0.f);
    #pragma unroll
    for (int j = 0; j < RUN; ++j) {
        int   rj = (&r4[j >> 2].x)[j & 3];
        float vj = (&v[j >> 2].x)[j & 3];
        float2 lo = __half22float2(g[j].lo);
        float2 hi = __half22float2(g[j].hi);
        if (rj != cur) {                 // rare: ~0.5 times per 8-run
            int s = cur - rfirst;
            if (s < NSLOTS) {
                atomicAdd(&sl[wv][s][0], acc.x);
                atomicAdd(&sl[wv][s][1], acc.y);
                atomicAdd(&sl[wv][s][2], acc.z);
                atomicAdd(&sl[wv][s][3], acc.w);
            } else {
                global_flush(out, cur, acc);   // span overflow: ~never
            }
            acc = make_float4(0.f, 0.f, 0.f, 0.f);
            cur = rj;
        }
        acc.x += vj * lo.x;
        acc.y += vj * lo.y;
        acc.z += vj * hi.x;
        acc.w += vj * hi.y;
    }
    {
        int s = cur - rfirst;
        if (s < NSLOTS) {
            atomicAdd(&sl[wv][s][0], acc.x);
            atomicAdd(&sl[wv][s][1], acc.y);
            atomicAdd(&sl[wv][s][2], acc.z);
            atomicAdd(&sl[wv][s][3], acc.w);
        } else {
            global_flush(out, cur, acc);
        }
    }

    __syncthreads();

    // ---- epilogue: one slot per lane ----
    int span = rlast - rfirst;
    if (lane <= span && lane < NSLOTS) {
        float ax = sl[wv][lane][0];
        float ay = sl[wv][lane][1];
        float az = sl[wv][lane][2];
        float aw = sl[wv][lane][3];
        int rr = rfirst + lane;
        int ix = rr >> 9;
        int iz = rr & (NZ - 1);
        int o = iz * NX + ix;
        if (lane == 0 || rr == rlast) {
            // boundary row: may be shared with neighbor wave
            atomicAdd(&out[0 * NROWS + o], ax);
            atomicAdd(&out[1 * NROWS + o], ay);
            atomicAdd(&out[2 * NROWS + o], az);
            atomicAdd(&out[3 * NROWS + o], aw);
        } else {
            // interior row: all its nnz are in this wave (rows sorted)
            out[0 * NROWS + o] = ax;
            out[1 * NROWS + o] = ay;
            out[2 * NROWS + o] = az;
            out[3 * NROWS + o] = aw;
        }
    }
}

// Fallback (workspace too small): inline bounds + direct fp32 gather from x.
__global__ void __launch_bounds__(256) spmm_direct_kernel(
        const float* __restrict__ x,
        const float* __restrict__ vals,
        const int* __restrict__ rows,
        const int* __restrict__ cols,
        int nnz,
        float* __restrict__ out) {
    int r = (blockIdx.x << 2) + (threadIdx.x >> 6);
    int lane = threadIdx.x & 63;
    int start, end;
    {
        int lo = 0, hi = nnz;
        while (lo < hi) { int mid = (lo + hi) >> 1; if (rows[mid] < r) lo = mid + 1; else hi = mid; }
        start = lo;
        hi = nnz;
        int key = r + 1;
        while (lo < hi) { int mid = (lo + hi) >> 1; if (rows[mid] < key) lo = mid + 1; else hi = mid; }
        end = lo;
    }
    float4 acc = {0.f, 0.f, 0.f, 0.f};
    for (int i = start + lane; i < end; i += 64) {
        float v = vals[i];
        int col = cols[i];
        int cc = col & (NC - 1);
        int ss = col >> 7;
        int b = cc * NS + ss;
        acc.x += v * x[b];
        acc.y += v * x[b + 1 * NC * NS];
        acc.z += v * x[b + 2 * NC * NS];
        acc.w += v * x[b + 3 * NC * NS];
    }
    #pragma unroll
    for (int off = 32; off >= 1; off >>= 1) {
        acc.x += __shfl_xor(acc.x, off, 64);
        acc.y += __shfl_xor(acc.y, off, 64);
        acc.z += __shfl_xor(acc.z, off, 64);
        acc.w += __shfl_xor(acc.w, off, 64);
    }
    if (lane < 4) {
        float o = (lane == 0) ? acc.x : (lane == 1) ? acc.y : (lane == 2) ? acc.z : acc.w;
        int ix = r >> 9;
        int iz = r & (NZ - 1);
        out[lane * NROWS + iz * NX + ix] = o;
    }
}

extern "C" void kernel_launch(void* const* d_in, const int* in_sizes, int n_in,
                              void* d_out, int out_size, void* d_ws, size_t ws_size,
                              hipStream_t stream) {
    const float* x        = (const float*)d_in[0];
    const float* csr_vals = (const float*)d_in[1];
    const int*   csr_rows = (const int*)d_in[2];   // int32 per harness contract
    const int*   csr_cols = (const int*)d_in[3];
    float* out = (float*)d_out;
    int nnz = in_sizes[1];

    size_t need = (size_t)NCOLS * sizeof(Half4);   // 2MB
    if (ws_size >= need) {
        Half4* rhs = (Half4*)d_ws;
        hipMemsetAsync(out, 0, (size_t)out_size * sizeof(float), stream);
        pack_rhs_kernel<<<(NCOLS + 255) / 256, 256, 0, stream>>>(x, rhs);
        int nblocks = (nnz + 4 * WAVE_NNZ - 1) / (4 * WAVE_NNZ);   // 8192 blocks, 32K waves
        spmm_seg_kernel<<<nblocks, 256, 0, stream>>>(csr_vals, csr_cols, csr_rows,
                                                     rhs, out, nnz);
    } else {
        spmm_direct_kernel<<<NROWS / 4, 256, 0, stream>>>(x, csr_vals, csr_rows, csr_cols, nnz, out);
    }
}